// Round 5
// baseline (166.491 us; speedup 1.0000x reference)
//
#include <hip/hip_runtime.h>

using bf16x8 = __attribute__((ext_vector_type(8))) short;
using u16x8  = __attribute__((ext_vector_type(8))) unsigned short;
using f32x4  = __attribute__((ext_vector_type(4))) float;

#define LSEQ   4096
#define NH     16
#define DH     64
#define WIN    256
#define DM     1024

// async global->LDS, 16B per lane; LDS dest is wave-uniform base + lane*16
__device__ __forceinline__ void gl2lds16(const void* g, void* l) {
  __builtin_amdgcn_global_load_lds(
      (const __attribute__((address_space(1))) unsigned int*)g,
      (__attribute__((address_space(3))) unsigned int*)l,
      16, 0, 0);
}

// fp32 -> bf16 RNE (finite inputs only)
__device__ __forceinline__ unsigned short f2bf(float f) {
  unsigned int u = __float_as_uint(f);
  u += 0x7fffu + ((u >> 16) & 1u);
  return (unsigned short)(u >> 16);
}

// ---- fp32 -> bf16, exact-size flat kernel over the contiguous ws image ----
__global__ __launch_bounds__(256) void cvt_all(
    const float* __restrict__ x,  const float* __restrict__ wq,
    const float* __restrict__ wk, const float* __restrict__ wv,
    const float* __restrict__ wo, unsigned short* __restrict__ dst)
{
  const size_t i = ((size_t)blockIdx.x * 256 + threadIdx.x) * 8;
  const size_t XN = (size_t)LSEQ * DM;          // 4M
  const float* src;
  size_t off;
  if (i < XN) { src = x; off = i; }
  else {
    const size_t j = i - XN;
    const int s = (int)(j >> 20);                // 1M elems per weight
    off = j & ((1u << 20) - 1);
    src = (s == 0) ? wq : (s == 1) ? wk : (s == 2) ? wv : wo;
  }
  const f32x4 f0 = *(const f32x4*)(src + off);
  const f32x4 f1 = *(const f32x4*)(src + off + 4);
  u16x8 o;
  o[0] = f2bf(f0[0]); o[1] = f2bf(f0[1]); o[2] = f2bf(f0[2]); o[3] = f2bf(f0[3]);
  o[4] = f2bf(f1[0]); o[5] = f2bf(f1[1]); o[6] = f2bf(f1[2]); o[7] = f2bf(f1[3]);
  *(u16x8*)(dst + i) = o;
}

// ============================================================================
// proj2 — R18: merged QKV projections, 2-phase (proven semantics), geometry
// 256x128 tile, 8 waves (4M x 2N), BK=64, R16-verified XOR swizzle.
// Rationale vs R16 proj_gemm (42.9 us, MfmaUtil 21%): 256 MFMA per
// barrier-pair per block (2x), 48 KB LDS -> 3 blocks/CU co-resident (m114
// overlap hides the vmcnt(0)+barrier drain), 384 blocks = 1.5 rounds at
// capacity (vs 768 / 3 rounds -> fewer exposed prologue/epilogue tails).
// Rationale vs R17 proj8 (8-phase 256^2): that geometry forces 192 blocks =
// 1 block/CU = 25% idle CUs, cancelling its per-CU gain.
// Grid 384: id<256 -> QK (A=X M=4096 16 tiles, B=[Wq||Wk] N=2048 16 tiles);
//           id>=256 -> V^T (A=Wv M=1024 4 tiles, B=X N=4096 32 tiles).
// k accumulation order identical to R16 (kt asc, s asc) -> same numerics.
// ============================================================================
__global__ __launch_bounds__(512) void proj2(
    const unsigned short* __restrict__ X,
    const unsigned short* __restrict__ Wqk,   // Wq with Wk contiguous after
    const unsigned short* __restrict__ Wv,
    unsigned short* __restrict__ Qo,
    unsigned short* __restrict__ Ko,
    unsigned short* __restrict__ Vt)
{
  __shared__ __align__(16) unsigned short As[256 * 64];   // 32 KiB
  __shared__ __align__(16) unsigned short Bs[128 * 64];   // 16 KiB

  const int id   = blockIdx.x;
  const bool qk  = (id < 256);
  const int tid  = threadIdx.x;
  const int lane = tid & 63;
  const int wave = tid >> 6;          // 0..7
  const int wm   = wave >> 1;         // M quarter (0..3), 64 rows each
  const int wn   = wave & 1;          // N half    (0..1), 64 cols each
  const int fr   = lane & 15, quad = lane >> 4;
  const int swz  = fr & 7;

  int m0, n0;
  const unsigned short *Ag, *Bg;
  if (qk) {
    m0 = (id & 15) * 256;             // token rows
    n0 = (id >> 4) * 128;             // rows of [Wq||Wk]
    Ag = X; Bg = Wqk;
  } else {
    const int v = id - 256;
    m0 = (v & 3) * 256;               // d rows of Wv
    n0 = (v >> 2) * 128;              // token cols
    Ag = Wv; Bg = X;
  }

  const f32x4 zero = {0.f, 0.f, 0.f, 0.f};
  f32x4 acc[4][4];
  #pragma unroll
  for (int f = 0; f < 4; ++f)
    #pragma unroll
    for (int g = 0; g < 4; ++g)
      acc[f][g] = zero;

  // staging: A 2048 chunks (cc=0..3), B 1024 chunks (cc=0..1); thread t
  // handles chunk c = t + cc*512; row = c>>3, slot = c&7, global chunk
  // gp = slot ^ (row&7) (inverse swizzle on source; LDS dest linear).
  const unsigned short* ga[4];
  char* la[4];
  #pragma unroll
  for (int cc = 0; cc < 4; ++cc) {
    const int c = tid + cc * 512;
    const int row = c >> 3;
    const int gp  = (c & 7) ^ (row & 7);
    ga[cc] = Ag + (size_t)(m0 + row) * DM + gp * 8;
    la[cc] = (char*)As + c * 16;
  }
  const unsigned short* gb[2];
  char* lb[2];
  #pragma unroll
  for (int cc = 0; cc < 2; ++cc) {
    const int c = tid + cc * 512;
    const int row = c >> 3;
    const int gp  = (c & 7) ^ (row & 7);
    gb[cc] = Bg + (size_t)(n0 + row) * DM + gp * 8;
    lb[cc] = (char*)Bs + c * 16;
  }

  for (int kt = 0; kt < DM; kt += 64) {
    #pragma unroll
    for (int cc = 0; cc < 4; ++cc)
      gl2lds16(ga[cc] + kt, la[cc]);
    #pragma unroll
    for (int cc = 0; cc < 2; ++cc)
      gl2lds16(gb[cc] + kt, lb[cc]);
    __syncthreads();

    #pragma unroll
    for (int s = 0; s < 2; ++s) {
      bf16x8 a[4], b[4];
      #pragma unroll
      for (int t = 0; t < 4; ++t)
        a[t] = *(const bf16x8*)(As + (wm * 64 + t * 16 + fr) * 64
                                   + (((s * 4 + quad) ^ swz) * 8));
      #pragma unroll
      for (int t = 0; t < 4; ++t)
        b[t] = *(const bf16x8*)(Bs + (wn * 64 + t * 16 + fr) * 64
                                   + (((s * 4 + quad) ^ swz) * 8));
      __builtin_amdgcn_s_setprio(1);
      #pragma unroll
      for (int i = 0; i < 4; ++i)
        #pragma unroll
        for (int j = 0; j < 4; ++j)
          acc[i][j] = __builtin_amdgcn_mfma_f32_16x16x32_bf16(a[i], b[j], acc[i][j], 0, 0, 0);
      __builtin_amdgcn_s_setprio(0);
    }
    __syncthreads();
  }

  // ---- epilogue
  const int cn = fr;
  if (qk) {
    const bool isK = (n0 >= 1024);                   // tile is entirely Q or K
    const float qscl = isK ? 1.0f : 0.180336881f;    // 0.125 * log2(e)
    unsigned short* O = isK ? Ko : Qo;
    const int nb = isK ? (n0 - 1024) : n0;
    #pragma unroll
    for (int f = 0; f < 4; ++f)
      #pragma unroll
      for (int g = 0; g < 4; ++g)
        #pragma unroll
        for (int r = 0; r < 4; ++r) {
          const int row = m0 + wm * 64 + f * 16 + quad * 4 + r;
          const int col = nb + wn * 64 + g * 16 + cn;
          const int h = col >> 6, d = col & 63;
          O[(size_t)(h * LSEQ + row) * DH + d] = f2bf(acc[f][g][r] * qscl);
        }
  } else {
    #pragma unroll
    for (int f = 0; f < 4; ++f)
      #pragma unroll
      for (int g = 0; g < 4; ++g)
        #pragma unroll
        for (int r = 0; r < 4; ++r) {
          const int row = m0 + wm * 64 + f * 16 + quad * 4 + r;   // d
          const int col = n0 + wn * 64 + g * 16 + cn;             // token
          Vt[(size_t)row * LSEQ + col] = f2bf(acc[f][g][r]);
        }
  }
}

// Output projection, 64x128 tiles, grid (64,8) = 512 blocks = 2/CU.
// R16: BK=64 + swizzle: 16 steps, 16 MFMA per barrier-pair. LDS 24 KB.
__global__ __launch_bounds__(256) void out_gemm(
    const unsigned short* __restrict__ X,
    const unsigned short* __restrict__ W,
    float* __restrict__ O)
{
  __shared__ unsigned short As2[64 * 64];
  __shared__ unsigned short Bs[128 * 64];
  const int m0 = blockIdx.x * 64;
  const int n0 = blockIdx.y * 128;
  const int tid  = threadIdx.x;
  const int lane = tid & 63;
  const int wave = tid >> 6;
  const int wm = wave >> 1, wn = wave & 1;
  const int fr = lane & 15, quad = lane >> 4;

  const f32x4 zero = {0.f, 0.f, 0.f, 0.f};
  f32x4 acc[2][4];
  #pragma unroll
  for (int i = 0; i < 2; ++i)
    #pragma unroll
    for (int j = 0; j < 4; ++j)
      acc[i][j] = zero;

  const unsigned short* ga[2];
  char* la[2];
  #pragma unroll
  for (int cc = 0; cc < 2; ++cc) {
    const int c = tid + cc * 256;
    const int row = c >> 3;
    const int gpp = (c & 7) ^ (row & 7);
    ga[cc] = X + (size_t)(m0 + row) * DM + gpp * 8;
    la[cc] = (char*)As2 + c * 16;
  }
  const unsigned short* gb[4];
  char* lb[4];
  #pragma unroll
  for (int cc = 0; cc < 4; ++cc) {
    const int c = tid + cc * 256;
    const int row = c >> 3;
    const int gpp = (c & 7) ^ (row & 7);
    gb[cc] = W + (size_t)(n0 + row) * DM + gpp * 8;
    lb[cc] = (char*)Bs + c * 16;
  }

  const int sw = fr & 7;
  for (int kt = 0; kt < DM; kt += 64) {
    #pragma unroll
    for (int cc = 0; cc < 2; ++cc)
      gl2lds16(ga[cc] + kt, la[cc]);
    #pragma unroll
    for (int cc = 0; cc < 4; ++cc)
      gl2lds16(gb[cc] + kt, lb[cc]);
    __syncthreads();

    #pragma unroll
    for (int s = 0; s < 2; ++s) {
      bf16x8 a[2], b[4];
      #pragma unroll
      for (int t = 0; t < 2; ++t)
        a[t] = *(const bf16x8*)(As2 + (wm * 32 + t * 16 + fr) * 64
                                    + (((s * 4 + quad) ^ sw) * 8));
      #pragma unroll
      for (int t = 0; t < 4; ++t)
        b[t] = *(const bf16x8*)(Bs + (wn * 64 + t * 16 + fr) * 64
                                   + (((s * 4 + quad) ^ sw) * 8));
      #pragma unroll
      for (int i = 0; i < 2; ++i)
        #pragma unroll
        for (int j = 0; j < 4; ++j)
          acc[i][j] = __builtin_amdgcn_mfma_f32_16x16x32_bf16(a[i], b[j], acc[i][j], 0, 0, 0);
    }
    __syncthreads();
  }

  const int cn = lane & 15;
  #pragma unroll
  for (int i = 0; i < 2; ++i)
    #pragma unroll
    for (int j = 0; j < 4; ++j)
      #pragma unroll
      for (int r = 0; r < 4; ++r) {
        const int row = m0 + wm * 32 + i * 16 + quad * 4 + r;
        const int col = n0 + wn * 64 + j * 16 + cn;
        O[(size_t)row * DM + col] = acc[i][j][r];
      }
}

// Flash sliding-window attention (R15 form, unchanged):
// 8 waves x 128 queries per block; K/V staged once per block into padded LDS
// (double-buffered, reg-staged); waves skip fully-masked tiles; mask VALU
// only on partially-masked tiles; T5 setprio around MFMA clusters.
#define PSTR 72
__global__ __launch_bounds__(512) void attn_fwd(
    const unsigned short* __restrict__ Q,
    const unsigned short* __restrict__ K,
    const unsigned short* __restrict__ Vt,
    unsigned short* __restrict__ Oa)
{
  __shared__ unsigned short Ks[2][64 * PSTR];   // 9216 B each
  __shared__ unsigned short Vs[2][64 * PSTR];
  __shared__ unsigned short Pl[8][16 * PSTR];   // per-wave P tiles
  const int id   = blockIdx.x;
  const int h    = (id & 7) | ((id >> 8) << 3);
  const int bq0  = ((id >> 3) & 31) * 128;
  const int tid  = threadIdx.x;
  const int wave = tid >> 6;
  const int lane = tid & 63;
  const int n = lane & 15, quad = lane >> 4;
  const int q0 = bq0 + wave * 16;
  unsigned short* pl = Pl[wave];

  const size_t qbase = ((size_t)(h * LSEQ + q0 + n)) * DH + quad * 8;
  const bf16x8 aq0 = *(const bf16x8*)(Q + qbase);   // Q pre-scaled by 0.125*log2e
  const bf16x8 aq1 = *(const bf16x8*)(Q + qbase + 32);

  const int lo = (bq0 >= WIN) ? (bq0 - WIN) : 0;    // first 64-key tile
  const int hi = bq0 + 128;

  // staging map: 512 x 16B chunks per tile; thread t handles chunk t.
  const int krow = tid >> 3, part = tid & 7;
  const size_t kg = ((size_t)(h * LSEQ + krow)) * DH + part * 8;
  const size_t vg = ((size_t)(h * DH + krow)) * LSEQ + part * 8;
  const int ld = krow * PSTR + part * 8;

  // prologue: stage tile 0 into buffer 0
  {
    *(bf16x8*)(Ks[0] + ld) = *(const bf16x8*)(K  + kg + (size_t)lo * DH);
    *(bf16x8*)(Vs[0] + ld) = *(const bf16x8*)(Vt + vg + lo);
  }
  __syncthreads();

  const f32x4 zero = {0.f, 0.f, 0.f, 0.f};
  f32x4 acc[4] = {zero, zero, zero, zero};
  float li[4] = {0.f, 0.f, 0.f, 0.f};

  int t = 0;
  for (int jb = lo; jb < hi; jb += 64, ++t) {
    const int buf = t & 1;
    const bool more = (jb + 64 < hi);
    // ---- issue next tile's global loads (overlap entire compute phase)
    bf16x8 nk, nv;
    if (more) {
      nk = *(const bf16x8*)(K  + kg + (size_t)(jb + 64) * DH);
      nv = *(const bf16x8*)(Vt + vg + (jb + 64));
    }
    // wave-level relevance: any of this wave's 16 rows attends a key here?
    const bool active = (jb <= q0 + 15) && (jb + 63 >= q0 - (WIN - 1));
    if (active) {
      const unsigned short* ks = Ks[buf];
      const unsigned short* vs = Vs[buf];
      // ---- QK scores from LDS K
      f32x4 s[4];
      __builtin_amdgcn_s_setprio(1);
      #pragma unroll
      for (int u = 0; u < 4; ++u) {
        const bf16x8 kb0 = *(const bf16x8*)(ks + (u * 16 + n) * PSTR + quad * 8);
        const bf16x8 kb1 = *(const bf16x8*)(ks + (u * 16 + n) * PSTR + 32 + quad * 8);
        f32x4 c = zero;
        c = __builtin_amdgcn_mfma_f32_16x16x32_bf16(aq0, kb0, c, 0, 0, 0);
        c = __builtin_amdgcn_mfma_f32_16x16x32_bf16(aq1, kb1, c, 0, 0, 0);
        s[u] = c;
      }
      __builtin_amdgcn_s_setprio(0);
      // ---- fixed-shift exp2 + per-lane partial denominator
      const bool nomask = (jb + 63 <= q0) && (jb >= q0 + 15 - (WIN - 1));
      if (nomask) {
        #pragma unroll
        for (int u = 0; u < 4; ++u)
          #pragma unroll
          for (int r = 0; r < 4; ++r) {
            const float e = __builtin_exp2f(s[u][r] - 32.0f);
            s[u][r] = e;
            li[r] += e;
          }
      } else {
        #pragma unroll
        for (int u = 0; u < 4; ++u)
          #pragma unroll
          for (int r = 0; r < 4; ++r) {
            const int qi = q0 + quad * 4 + r;
            const int kj = jb + u * 16 + n;
            const bool ok = (kj <= qi) && (kj + WIN > qi);
            const float e = __builtin_exp2f(ok ? s[u][r] - 32.0f : -1e30f);
            s[u][r] = e;
            li[r] += e;
          }
      }
      // ---- P: C-layout regs -> per-wave LDS -> A-operand layout
      #pragma unroll
      for (int u = 0; u < 4; ++u)
        #pragma unroll
        for (int r = 0; r < 4; ++r)
          pl[(quad * 4 + r) * PSTR + u * 16 + n] = f2bf(s[u][r]);
      asm volatile("s_waitcnt lgkmcnt(0)" ::: "memory");   // wave-private LDS fence
      const bf16x8 pa0 = *(const bf16x8*)(pl + n * PSTR + quad * 8);
      const bf16x8 pa1 = *(const bf16x8*)(pl + n * PSTR + 32 + quad * 8);
      // ---- PV from LDS V
      __builtin_amdgcn_s_setprio(1);
      #pragma unroll
      for (int ct = 0; ct < 4; ++ct) {
        const bf16x8 vb0 = *(const bf16x8*)(vs + (ct * 16 + n) * PSTR + quad * 8);
        const bf16x8 vb1 = *(const bf16x8*)(vs + (ct * 16 + n) * PSTR + 32 + quad * 8);
        acc[ct] = __builtin_amdgcn_mfma_f32_16x16x32_bf16(pa0, vb0, acc[ct], 0, 0, 0);
        acc[ct] = __builtin_amdgcn_mfma_f32_16x16x32_bf16(pa1, vb1, acc[ct], 0, 0, 0);
      }
      __builtin_amdgcn_s_setprio(0);
    }
    // ---- write next tile into the other buffer, then one barrier
    if (more) {
      *(bf16x8*)(Ks[buf ^ 1] + ld) = nk;
      *(bf16x8*)(Vs[buf ^ 1] + ld) = nv;
    }
    __syncthreads();
  }

  // ---- single cross-lane denominator reduction
  float rd[4];
  #pragma unroll
  for (int r = 0; r < 4; ++r) {
    float v = li[r];
    v += __shfl_xor(v, 1);
    v += __shfl_xor(v, 2);
    v += __shfl_xor(v, 4);
    v += __shfl_xor(v, 8);
    rd[r] = 1.0f / v;
  }
  #pragma unroll
  for (int ct = 0; ct < 4; ++ct)
    #pragma unroll
    for (int r = 0; r < 4; ++r) {
      const int row = q0 + quad * 4 + r;
      const int col = h * DH + ct * 16 + n;
      Oa[(size_t)row * DM + col] = f2bf(acc[ct][r] * rd[r]);
    }
}

extern "C" void kernel_launch(void* const* d_in, const int* in_sizes, int n_in,
                              void* d_out, int out_size, void* d_ws, size_t ws_size,
                              hipStream_t stream) {
  const float* x  = (const float*)d_in[0];
  const float* Wq = (const float*)d_in[1];
  const float* Wk = (const float*)d_in[2];
  const float* Wv = (const float*)d_in[3];
  const float* Wo = (const float*)d_in[4];
  float* out = (float*)d_out;               // fp32 output (proven R6)

  unsigned short* xb  = (unsigned short*)d_ws;            // [L][DM]    8 MiB
  unsigned short* Wqb = xb  + (size_t)LSEQ * DM;          // 2 MiB each
  unsigned short* Wkb = Wqb + (size_t)DM * DM;            // contiguous after Wq
  unsigned short* Wvb = Wkb + (size_t)DM * DM;
  unsigned short* Wob = Wvb + (size_t)DM * DM;
  unsigned short* Q    = Wob + (size_t)DM * DM;           // [H][L][64] 8 MiB (pre-scaled)
  unsigned short* K    = Q   + (size_t)LSEQ * DM;
  unsigned short* Vt   = K   + (size_t)LSEQ * DM;         // [H*DH][L]
  unsigned short* Attn = Vt  + (size_t)LSEQ * DM;         // [L][DM]
  // total 48 MiB (ws >= 64 MiB, proven R4)

  cvt_all<<<dim3(4096), 256, 0, stream>>>(x, Wq, Wk, Wv, Wo, xb);
  proj2<<<dim3(384), 512, 0, stream>>>(xb, Wqb, Wvb, Q, K, Vt);
  attn_fwd<<<dim3(512), 512, 0, stream>>>(Q, K, Vt, Attn);
  out_gemm<<<dim3(64, 8), 256, 0, stream>>>(Attn, Wob, out);
}

// Round 6
// 152.787 us; speedup vs baseline: 1.0897x; 1.0897x over previous
//
#include <hip/hip_runtime.h>

using bf16x8 = __attribute__((ext_vector_type(8))) short;
using u16x8  = __attribute__((ext_vector_type(8))) unsigned short;
using f32x4  = __attribute__((ext_vector_type(4))) float;

#define LSEQ   4096
#define NH     16
#define DH     64
#define WIN    256
#define DM     1024

// async global->LDS, 16B per lane; LDS dest is wave-uniform base + lane*16
__device__ __forceinline__ void gl2lds16(const void* g, void* l) {
  __builtin_amdgcn_global_load_lds(
      (const __attribute__((address_space(1))) unsigned int*)g,
      (__attribute__((address_space(3))) unsigned int*)l,
      16, 0, 0);
}

// fp32 -> bf16 RNE (finite inputs only)
__device__ __forceinline__ unsigned short f2bf(float f) {
  unsigned int u = __float_as_uint(f);
  u += 0x7fffu + ((u >> 16) & 1u);
  return (unsigned short)(u >> 16);
}

// ---- fp32 -> bf16, exact-size flat kernel over the contiguous ws image ----
__global__ __launch_bounds__(256) void cvt_all(
    const float* __restrict__ x,  const float* __restrict__ wq,
    const float* __restrict__ wk, const float* __restrict__ wv,
    const float* __restrict__ wo, unsigned short* __restrict__ dst)
{
  const size_t i = ((size_t)blockIdx.x * 256 + threadIdx.x) * 8;
  const size_t XN = (size_t)LSEQ * DM;          // 4M
  const float* src;
  size_t off;
  if (i < XN) { src = x; off = i; }
  else {
    const size_t j = i - XN;
    const int s = (int)(j >> 20);                // 1M elems per weight
    off = j & ((1u << 20) - 1);
    src = (s == 0) ? wq : (s == 1) ? wk : (s == 2) ? wv : wo;
  }
  const f32x4 f0 = *(const f32x4*)(src + off);
  const f32x4 f1 = *(const f32x4*)(src + off + 4);
  u16x8 o;
  o[0] = f2bf(f0[0]); o[1] = f2bf(f0[1]); o[2] = f2bf(f0[2]); o[3] = f2bf(f0[3]);
  o[4] = f2bf(f1[0]); o[5] = f2bf(f1[1]); o[6] = f2bf(f1[2]); o[7] = f2bf(f1[3]);
  *(u16x8*)(dst + i) = o;
}

// ============================================================================
// gemm_tile_db — R19: 128x128 NT tile, BK=64, R16-verified XOR swizzle,
// DOUBLE-BUFFERED with stage-ahead (T3 minimal recipe, m248v2: +10% @ K=1024).
// Per K-step: issue next tile's 8 gl2lds into buf^1 FIRST, then ds_read +
// 32 MFMA on buf, then ONE __syncthreads (was 2 barriers + immediate drain).
// The barrier's implicit vmcnt(0) now has the whole compute phase between
// load-issue and wait. Hazards: reads of buf consumed by MFMA before the
// barrier; writes into buf land next iter after it (standard dbuf).
// LDS 64 KiB -> 2 blocks/CU (was 3); m248 says pipelining beats that loss.
// k-accumulation order identical to R16 -> same numerics.
// Grid-fill lesson (R14/R17/R18, 3x confirmed): >=2 blocks/CU co-resident
// required; 768 blocks keeps that.
// ============================================================================
__device__ __forceinline__ void gemm_tile_db(
    const unsigned short* __restrict__ X,
    const unsigned short* __restrict__ W,
    int m0, int n0,
    unsigned short* As0, unsigned short* Bs0,   // [2][128*64] each
    f32x4 (&acc)[4][4])
{
  const int tid  = threadIdx.x;
  const int lane = tid & 63;
  const int wave = tid >> 6;
  const int wm = wave >> 1, wn = wave & 1;
  const int fr = lane & 15, quad = lane >> 4;
  const int sw = fr & 7;

  const f32x4 zero = {0.f, 0.f, 0.f, 0.f};
  #pragma unroll
  for (int i = 0; i < 4; ++i)
    #pragma unroll
    for (int j = 0; j < 4; ++j)
      acc[i][j] = zero;

  // staging: 1024 chunks per operand, thread t handles c = t + cc*256;
  // row = c>>3, slot = c&7, global chunk gp = slot^(row&7) (inverse swizzle
  // on source; LDS dest linear — rule #21).
  const unsigned short* ga[4];
  const unsigned short* gb[4];
  int lc[4];
  #pragma unroll
  for (int cc = 0; cc < 4; ++cc) {
    const int c = tid + cc * 256;
    const int row = c >> 3;
    const int gp  = (c & 7) ^ (row & 7);
    ga[cc] = X + (size_t)(m0 + row) * DM + gp * 8;
    gb[cc] = W + (size_t)(n0 + row) * DM + gp * 8;
    lc[cc] = c * 16;                       // byte offset within a buffer
  }
  char* laA = (char*)As0;
  char* laB = (char*)Bs0;

  // prologue: stage tile 0 into buffer 0
  #pragma unroll
  for (int cc = 0; cc < 4; ++cc) {
    gl2lds16(ga[cc], laA + lc[cc]);
    gl2lds16(gb[cc], laB + lc[cc]);
  }
  __syncthreads();

  #define PITER(KT, CUR, NXT)                                                 \
    do {                                                                      \
      if ((KT) + 64 < DM) {                                                   \
        _Pragma("unroll")                                                     \
        for (int cc = 0; cc < 4; ++cc) {                                      \
          gl2lds16(ga[cc] + (KT) + 64, laA + (NXT) * 16384 + lc[cc]);         \
          gl2lds16(gb[cc] + (KT) + 64, laB + (NXT) * 16384 + lc[cc]);         \
        }                                                                     \
      }                                                                       \
      const unsigned short* As_ = As0 + (CUR) * 8192;                         \
      const unsigned short* Bs_ = Bs0 + (CUR) * 8192;                         \
      _Pragma("unroll")                                                       \
      for (int s = 0; s < 2; ++s) {                                           \
        bf16x8 a[4], b[4];                                                    \
        _Pragma("unroll")                                                     \
        for (int t = 0; t < 4; ++t)                                           \
          a[t] = *(const bf16x8*)(As_ + (wm * 64 + t * 16 + fr) * 64          \
                                      + (((s * 4 + quad) ^ sw) * 8));         \
        _Pragma("unroll")                                                     \
        for (int t = 0; t < 4; ++t)                                           \
          b[t] = *(const bf16x8*)(Bs_ + (wn * 64 + t * 16 + fr) * 64          \
                                      + (((s * 4 + quad) ^ sw) * 8));         \
        __builtin_amdgcn_s_setprio(1);                                        \
        _Pragma("unroll")                                                     \
        for (int i = 0; i < 4; ++i)                                           \
          _Pragma("unroll")                                                   \
          for (int j = 0; j < 4; ++j)                                         \
            acc[i][j] = __builtin_amdgcn_mfma_f32_16x16x32_bf16(              \
                a[i], b[j], acc[i][j], 0, 0, 0);                              \
        __builtin_amdgcn_s_setprio(0);                                        \
      }                                                                       \
      __syncthreads();                                                        \
    } while (0)

  #pragma unroll 1
  for (int kt2 = 0; kt2 < DM; kt2 += 128) {
    PITER(kt2,      0, 1);
    PITER(kt2 + 64, 1, 0);
  }
  #undef PITER
}

// Merged projections, grid (768): id<512 Q/K; id>=512 V^T (operand swap)
__global__ __launch_bounds__(256) void proj_gemm(
    const unsigned short* __restrict__ X,
    const unsigned short* __restrict__ Wq,
    const unsigned short* __restrict__ Wk,
    const unsigned short* __restrict__ Wv,
    unsigned short* __restrict__ Qo,
    unsigned short* __restrict__ Ko,
    unsigned short* __restrict__ Vt)
{
  __shared__ __align__(16) unsigned short As[2 * 128 * 64];   // 32 KiB
  __shared__ __align__(16) unsigned short Bs[2 * 128 * 64];   // 32 KiB
  const int id = blockIdx.x;
  const int lane = threadIdx.x & 63;
  const int wave = threadIdx.x >> 6;
  const int wm = wave >> 1, wn = wave & 1;
  const int cn = lane & 15, quad = lane >> 4;
  f32x4 acc[4][4];

  if (id < 512) {
    const int m0   = (id & 31) * 128;
    const int by   = id >> 5;
    const int wsel = by >> 3;
    const int n0   = (by & 7) * 128;
    gemm_tile_db(X, wsel ? Wk : Wq, m0, n0, As, Bs, acc);

    const float qscl = wsel ? 1.0f : 0.180336881f;   // 0.125 * log2(e)
    unsigned short* O = wsel ? Ko : Qo;
    #pragma unroll
    for (int i = 0; i < 4; ++i)
      #pragma unroll
      for (int j = 0; j < 4; ++j)
        #pragma unroll
        for (int r = 0; r < 4; ++r) {
          const int row = m0 + wm * 64 + i * 16 + quad * 4 + r;
          const int col = n0 + wn * 64 + j * 16 + cn;
          const int h = col >> 6, d = col & 63;
          O[(size_t)(h * LSEQ + row) * DH + d] = f2bf(acc[i][j][r] * qscl);
        }
  } else {
    const int vid = id - 512;
    const int m0 = (vid & 7) * 128;    // d-block (H*DH)
    const int n0 = (vid >> 3) * 128;   // token-block
    gemm_tile_db(Wv, X, m0, n0, As, Bs, acc);

    #pragma unroll
    for (int i = 0; i < 4; ++i)
      #pragma unroll
      for (int j = 0; j < 4; ++j)
        #pragma unroll
        for (int r = 0; r < 4; ++r) {
          const int row = m0 + wm * 64 + i * 16 + quad * 4 + r;   // d
          const int col = n0 + wn * 64 + j * 16 + cn;             // token
          Vt[(size_t)row * LSEQ + col] = f2bf(acc[i][j][r]);
        }
  }
}

// Output projection, 64x128 tiles, grid (64,8) = 512 blocks = 2/CU.
// R16 form (frozen): BK=64 + swizzle, 16 steps, 16 MFMA per barrier-pair.
__global__ __launch_bounds__(256) void out_gemm(
    const unsigned short* __restrict__ X,
    const unsigned short* __restrict__ W,
    float* __restrict__ O)
{
  __shared__ unsigned short As2[64 * 64];
  __shared__ unsigned short Bs[128 * 64];
  const int m0 = blockIdx.x * 64;
  const int n0 = blockIdx.y * 128;
  const int tid  = threadIdx.x;
  const int lane = tid & 63;
  const int wave = tid >> 6;
  const int wm = wave >> 1, wn = wave & 1;
  const int fr = lane & 15, quad = lane >> 4;

  const f32x4 zero = {0.f, 0.f, 0.f, 0.f};
  f32x4 acc[2][4];
  #pragma unroll
  for (int i = 0; i < 2; ++i)
    #pragma unroll
    for (int j = 0; j < 4; ++j)
      acc[i][j] = zero;

  const unsigned short* ga[2];
  char* la[2];
  #pragma unroll
  for (int cc = 0; cc < 2; ++cc) {
    const int c = tid + cc * 256;
    const int row = c >> 3;
    const int gpp = (c & 7) ^ (row & 7);
    ga[cc] = X + (size_t)(m0 + row) * DM + gpp * 8;
    la[cc] = (char*)As2 + c * 16;
  }
  const unsigned short* gb[4];
  char* lb[4];
  #pragma unroll
  for (int cc = 0; cc < 4; ++cc) {
    const int c = tid + cc * 256;
    const int row = c >> 3;
    const int gpp = (c & 7) ^ (row & 7);
    gb[cc] = W + (size_t)(n0 + row) * DM + gpp * 8;
    lb[cc] = (char*)Bs + c * 16;
  }

  const int sw = fr & 7;
  for (int kt = 0; kt < DM; kt += 64) {
    #pragma unroll
    for (int cc = 0; cc < 2; ++cc)
      gl2lds16(ga[cc] + kt, la[cc]);
    #pragma unroll
    for (int cc = 0; cc < 4; ++cc)
      gl2lds16(gb[cc] + kt, lb[cc]);
    __syncthreads();

    #pragma unroll
    for (int s = 0; s < 2; ++s) {
      bf16x8 a[2], b[4];
      #pragma unroll
      for (int t = 0; t < 2; ++t)
        a[t] = *(const bf16x8*)(As2 + (wm * 32 + t * 16 + fr) * 64
                                    + (((s * 4 + quad) ^ sw) * 8));
      #pragma unroll
      for (int t = 0; t < 4; ++t)
        b[t] = *(const bf16x8*)(Bs + (wn * 64 + t * 16 + fr) * 64
                                   + (((s * 4 + quad) ^ sw) * 8));
      #pragma unroll
      for (int i = 0; i < 2; ++i)
        #pragma unroll
        for (int j = 0; j < 4; ++j)
          acc[i][j] = __builtin_amdgcn_mfma_f32_16x16x32_bf16(a[i], b[j], acc[i][j], 0, 0, 0);
    }
    __syncthreads();
  }

  const int cn = lane & 15;
  #pragma unroll
  for (int i = 0; i < 2; ++i)
    #pragma unroll
    for (int j = 0; j < 4; ++j)
      #pragma unroll
      for (int r = 0; r < 4; ++r) {
        const int row = m0 + wm * 32 + i * 16 + quad * 4 + r;
        const int col = n0 + wn * 64 + j * 16 + cn;
        O[(size_t)row * DM + col] = acc[i][j][r];
      }
}

// Flash sliding-window attention (R15 form, frozen):
// 8 waves x 128 queries per block; K/V staged once per block into padded LDS
// (double-buffered, reg-staged); waves skip fully-masked tiles; mask VALU
// only on partially-masked tiles; T5 setprio around MFMA clusters.
#define PSTR 72
__global__ __launch_bounds__(512) void attn_fwd(
    const unsigned short* __restrict__ Q,
    const unsigned short* __restrict__ K,
    const unsigned short* __restrict__ Vt,
    unsigned short* __restrict__ Oa)
{
  __shared__ unsigned short Ks[2][64 * PSTR];   // 9216 B each
  __shared__ unsigned short Vs[2][64 * PSTR];
  __shared__ unsigned short Pl[8][16 * PSTR];   // per-wave P tiles
  const int id   = blockIdx.x;
  const int h    = (id & 7) | ((id >> 8) << 3);
  const int bq0  = ((id >> 3) & 31) * 128;
  const int tid  = threadIdx.x;
  const int wave = tid >> 6;
  const int lane = tid & 63;
  const int n = lane & 15, quad = lane >> 4;
  const int q0 = bq0 + wave * 16;
  unsigned short* pl = Pl[wave];

  const size_t qbase = ((size_t)(h * LSEQ + q0 + n)) * DH + quad * 8;
  const bf16x8 aq0 = *(const bf16x8*)(Q + qbase);   // Q pre-scaled by 0.125*log2e
  const bf16x8 aq1 = *(const bf16x8*)(Q + qbase + 32);

  const int lo = (bq0 >= WIN) ? (bq0 - WIN) : 0;    // first 64-key tile
  const int hi = bq0 + 128;

  // staging map: 512 x 16B chunks per tile; thread t handles chunk t.
  const int krow = tid >> 3, part = tid & 7;
  const size_t kg = ((size_t)(h * LSEQ + krow)) * DH + part * 8;
  const size_t vg = ((size_t)(h * DH + krow)) * LSEQ + part * 8;
  const int ld = krow * PSTR + part * 8;

  // prologue: stage tile 0 into buffer 0
  {
    *(bf16x8*)(Ks[0] + ld) = *(const bf16x8*)(K  + kg + (size_t)lo * DH);
    *(bf16x8*)(Vs[0] + ld) = *(const bf16x8*)(Vt + vg + lo);
  }
  __syncthreads();

  const f32x4 zero = {0.f, 0.f, 0.f, 0.f};
  f32x4 acc[4] = {zero, zero, zero, zero};
  float li[4] = {0.f, 0.f, 0.f, 0.f};

  int t = 0;
  for (int jb = lo; jb < hi; jb += 64, ++t) {
    const int buf = t & 1;
    const bool more = (jb + 64 < hi);
    // ---- issue next tile's global loads (overlap entire compute phase)
    bf16x8 nk, nv;
    if (more) {
      nk = *(const bf16x8*)(K  + kg + (size_t)(jb + 64) * DH);
      nv = *(const bf16x8*)(Vt + vg + (jb + 64));
    }
    // wave-level relevance: any of this wave's 16 rows attends a key here?
    const bool active = (jb <= q0 + 15) && (jb + 63 >= q0 - (WIN - 1));
    if (active) {
      const unsigned short* ks = Ks[buf];
      const unsigned short* vs = Vs[buf];
      // ---- QK scores from LDS K
      f32x4 s[4];
      __builtin_amdgcn_s_setprio(1);
      #pragma unroll
      for (int u = 0; u < 4; ++u) {
        const bf16x8 kb0 = *(const bf16x8*)(ks + (u * 16 + n) * PSTR + quad * 8);
        const bf16x8 kb1 = *(const bf16x8*)(ks + (u * 16 + n) * PSTR + 32 + quad * 8);
        f32x4 c = zero;
        c = __builtin_amdgcn_mfma_f32_16x16x32_bf16(aq0, kb0, c, 0, 0, 0);
        c = __builtin_amdgcn_mfma_f32_16x16x32_bf16(aq1, kb1, c, 0, 0, 0);
        s[u] = c;
      }
      __builtin_amdgcn_s_setprio(0);
      // ---- fixed-shift exp2 + per-lane partial denominator
      const bool nomask = (jb + 63 <= q0) && (jb >= q0 + 15 - (WIN - 1));
      if (nomask) {
        #pragma unroll
        for (int u = 0; u < 4; ++u)
          #pragma unroll
          for (int r = 0; r < 4; ++r) {
            const float e = __builtin_exp2f(s[u][r] - 32.0f);
            s[u][r] = e;
            li[r] += e;
          }
      } else {
        #pragma unroll
        for (int u = 0; u < 4; ++u)
          #pragma unroll
          for (int r = 0; r < 4; ++r) {
            const int qi = q0 + quad * 4 + r;
            const int kj = jb + u * 16 + n;
            const bool ok = (kj <= qi) && (kj + WIN > qi);
            const float e = __builtin_exp2f(ok ? s[u][r] - 32.0f : -1e30f);
            s[u][r] = e;
            li[r] += e;
          }
      }
      // ---- P: C-layout regs -> per-wave LDS -> A-operand layout
      #pragma unroll
      for (int u = 0; u < 4; ++u)
        #pragma unroll
        for (int r = 0; r < 4; ++r)
          pl[(quad * 4 + r) * PSTR + u * 16 + n] = f2bf(s[u][r]);
      asm volatile("s_waitcnt lgkmcnt(0)" ::: "memory");   // wave-private LDS fence
      const bf16x8 pa0 = *(const bf16x8*)(pl + n * PSTR + quad * 8);
      const bf16x8 pa1 = *(const bf16x8*)(pl + n * PSTR + 32 + quad * 8);
      // ---- PV from LDS V
      __builtin_amdgcn_s_setprio(1);
      #pragma unroll
      for (int ct = 0; ct < 4; ++ct) {
        const bf16x8 vb0 = *(const bf16x8*)(vs + (ct * 16 + n) * PSTR + quad * 8);
        const bf16x8 vb1 = *(const bf16x8*)(vs + (ct * 16 + n) * PSTR + 32 + quad * 8);
        acc[ct] = __builtin_amdgcn_mfma_f32_16x16x32_bf16(pa0, vb0, acc[ct], 0, 0, 0);
        acc[ct] = __builtin_amdgcn_mfma_f32_16x16x32_bf16(pa1, vb1, acc[ct], 0, 0, 0);
      }
      __builtin_amdgcn_s_setprio(0);
    }
    // ---- write next tile into the other buffer, then one barrier
    if (more) {
      *(bf16x8*)(Ks[buf ^ 1] + ld) = nk;
      *(bf16x8*)(Vs[buf ^ 1] + ld) = nv;
    }
    __syncthreads();
  }

  // ---- single cross-lane denominator reduction
  float rd[4];
  #pragma unroll
  for (int r = 0; r < 4; ++r) {
    float v = li[r];
    v += __shfl_xor(v, 1);
    v += __shfl_xor(v, 2);
    v += __shfl_xor(v, 4);
    v += __shfl_xor(v, 8);
    rd[r] = 1.0f / v;
  }
  #pragma unroll
  for (int ct = 0; ct < 4; ++ct)
    #pragma unroll
    for (int r = 0; r < 4; ++r) {
      const int row = q0 + quad * 4 + r;
      const int col = h * DH + ct * 16 + n;
      Oa[(size_t)row * DM + col] = f2bf(acc[ct][r] * rd[r]);
    }
}

extern "C" void kernel_launch(void* const* d_in, const int* in_sizes, int n_in,
                              void* d_out, int out_size, void* d_ws, size_t ws_size,
                              hipStream_t stream) {
  const float* x  = (const float*)d_in[0];
  const float* Wq = (const float*)d_in[1];
  const float* Wk = (const float*)d_in[2];
  const float* Wv = (const float*)d_in[3];
  const float* Wo = (const float*)d_in[4];
  float* out = (float*)d_out;               // fp32 output (proven R6)

  unsigned short* xb  = (unsigned short*)d_ws;            // [L][DM]    8 MiB
  unsigned short* Wqb = xb  + (size_t)LSEQ * DM;          // 2 MiB each
  unsigned short* Wkb = Wqb + (size_t)DM * DM;
  unsigned short* Wvb = Wkb + (size_t)DM * DM;
  unsigned short* Wob = Wvb + (size_t)DM * DM;
  unsigned short* Q    = Wob + (size_t)DM * DM;           // [H][L][64] 8 MiB (pre-scaled)
  unsigned short* K    = Q   + (size_t)LSEQ * DM;
  unsigned short* Vt   = K   + (size_t)LSEQ * DM;         // [H*DH][L]
  unsigned short* Attn = Vt  + (size_t)LSEQ * DM;         // [L][DM]
  // total 48 MiB (ws >= 64 MiB, proven R4)

  cvt_all<<<dim3(4096), 256, 0, stream>>>(x, Wq, Wk, Wv, Wo, xb);
  proj_gemm<<<dim3(768), 256, 0, stream>>>(xb, Wqb, Wkb, Wvb, Q, K, Vt);
  attn_fwd<<<dim3(512), 512, 0, stream>>>(Q, K, Vt, Attn);
  out_gemm<<<dim3(64, 8), 256, 0, stream>>>(Attn, Wob, out);
}

// Round 7
// 151.594 us; speedup vs baseline: 1.0983x; 1.0079x over previous
//
#include <hip/hip_runtime.h>

using bf16x8 = __attribute__((ext_vector_type(8))) short;
using u16x8  = __attribute__((ext_vector_type(8))) unsigned short;
using f32x4  = __attribute__((ext_vector_type(4))) float;

#define LSEQ   4096
#define NH     16
#define DH     64
#define WIN    256
#define DM     1024

// async global->LDS, 16B per lane; LDS dest is wave-uniform base + lane*16
__device__ __forceinline__ void gl2lds16(const void* g, void* l) {
  __builtin_amdgcn_global_load_lds(
      (const __attribute__((address_space(1))) unsigned int*)g,
      (__attribute__((address_space(3))) unsigned int*)l,
      16, 0, 0);
}

// fp32 -> bf16 RNE (finite inputs only)
__device__ __forceinline__ unsigned short f2bf(float f) {
  unsigned int u = __float_as_uint(f);
  u += 0x7fffu + ((u >> 16) & 1u);
  return (unsigned short)(u >> 16);
}

// ---- fp32 -> bf16, exact-size flat kernel over the contiguous ws image ----
__global__ __launch_bounds__(256) void cvt_all(
    const float* __restrict__ x,  const float* __restrict__ wq,
    const float* __restrict__ wk, const float* __restrict__ wv,
    const float* __restrict__ wo, unsigned short* __restrict__ dst)
{
  const size_t i = ((size_t)blockIdx.x * 256 + threadIdx.x) * 8;
  const size_t XN = (size_t)LSEQ * DM;          // 4M
  const float* src;
  size_t off;
  if (i < XN) { src = x; off = i; }
  else {
    const size_t j = i - XN;
    const int s = (int)(j >> 20);                // 1M elems per weight
    off = j & ((1u << 20) - 1);
    src = (s == 0) ? wq : (s == 1) ? wk : (s == 2) ? wv : wo;
  }
  const f32x4 f0 = *(const f32x4*)(src + off);
  const f32x4 f1 = *(const f32x4*)(src + off + 4);
  u16x8 o;
  o[0] = f2bf(f0[0]); o[1] = f2bf(f0[1]); o[2] = f2bf(f0[2]); o[3] = f2bf(f0[3]);
  o[4] = f2bf(f1[0]); o[5] = f2bf(f1[1]); o[6] = f2bf(f1[2]); o[7] = f2bf(f1[3]);
  *(u16x8*)(dst + i) = o;
}

// ============================================================================
// gemm_tile_db8 — R20: 128x128 NT tile, BK=64, XOR swizzle, double-buffered
// stage-ahead (R19-proven schedule) with EIGHT waves (512 thr) instead of 4.
// Same per-block work and LDS (64 KiB, 2 blocks/CU); waves/CU 8 -> 16
// (2 -> 4 per SIMD) so co-resident waves at different phases hide the
// barrier's vmcnt(0) drain (m114 mechanism). Per-wave output 64x32,
// acc[4][2]; staging 4 gl2lds/thread/step (was 8).
// k-accumulation order identical to R16/R19 -> same numerics.
// ============================================================================
__device__ __forceinline__ void gemm_tile_db8(
    const unsigned short* __restrict__ X,
    const unsigned short* __restrict__ W,
    int m0, int n0,
    unsigned short* As0, unsigned short* Bs0,   // [2][128*64] each
    f32x4 (&acc)[4][2])
{
  const int tid  = threadIdx.x;
  const int lane = tid & 63;
  const int wave = tid >> 6;          // 0..7
  const int wm = wave >> 2;           // M half   (0..1), 64 rows
  const int wn = wave & 3;            // N quarter(0..3), 32 cols
  const int fr = lane & 15, quad = lane >> 4;
  const int sw = fr & 7;

  const f32x4 zero = {0.f, 0.f, 0.f, 0.f};
  #pragma unroll
  for (int i = 0; i < 4; ++i)
    #pragma unroll
    for (int j = 0; j < 2; ++j)
      acc[i][j] = zero;

  // staging: 1024 chunks per operand, thread t handles c = t + cc*512;
  // row = c>>3, slot = c&7, global chunk gp = slot^(row&7) (inverse swizzle
  // on source; LDS dest linear — rule #21).
  const unsigned short* ga[2];
  const unsigned short* gb[2];
  int lc[2];
  #pragma unroll
  for (int cc = 0; cc < 2; ++cc) {
    const int c = tid + cc * 512;
    const int row = c >> 3;
    const int gp  = (c & 7) ^ (row & 7);
    ga[cc] = X + (size_t)(m0 + row) * DM + gp * 8;
    gb[cc] = W + (size_t)(n0 + row) * DM + gp * 8;
    lc[cc] = c * 16;                       // byte offset within a buffer
  }
  char* laA = (char*)As0;
  char* laB = (char*)Bs0;

  // prologue: stage tile 0 into buffer 0
  #pragma unroll
  for (int cc = 0; cc < 2; ++cc) {
    gl2lds16(ga[cc], laA + lc[cc]);
    gl2lds16(gb[cc], laB + lc[cc]);
  }
  __syncthreads();

  #define PITER(KT, CUR, NXT)                                                 \
    do {                                                                      \
      if ((KT) + 64 < DM) {                                                   \
        _Pragma("unroll")                                                     \
        for (int cc = 0; cc < 2; ++cc) {                                      \
          gl2lds16(ga[cc] + (KT) + 64, laA + (NXT) * 16384 + lc[cc]);         \
          gl2lds16(gb[cc] + (KT) + 64, laB + (NXT) * 16384 + lc[cc]);         \
        }                                                                     \
      }                                                                       \
      const unsigned short* As_ = As0 + (CUR) * 8192;                         \
      const unsigned short* Bs_ = Bs0 + (CUR) * 8192;                         \
      _Pragma("unroll")                                                       \
      for (int s = 0; s < 2; ++s) {                                           \
        bf16x8 a[4], b[2];                                                    \
        _Pragma("unroll")                                                     \
        for (int t = 0; t < 4; ++t)                                           \
          a[t] = *(const bf16x8*)(As_ + (wm * 64 + t * 16 + fr) * 64          \
                                      + (((s * 4 + quad) ^ sw) * 8));         \
        _Pragma("unroll")                                                     \
        for (int t = 0; t < 2; ++t)                                           \
          b[t] = *(const bf16x8*)(Bs_ + (wn * 32 + t * 16 + fr) * 64          \
                                      + (((s * 4 + quad) ^ sw) * 8));         \
        __builtin_amdgcn_s_setprio(1);                                        \
        _Pragma("unroll")                                                     \
        for (int i = 0; i < 4; ++i)                                           \
          _Pragma("unroll")                                                   \
          for (int j = 0; j < 2; ++j)                                         \
            acc[i][j] = __builtin_amdgcn_mfma_f32_16x16x32_bf16(              \
                a[i], b[j], acc[i][j], 0, 0, 0);                              \
        __builtin_amdgcn_s_setprio(0);                                        \
      }                                                                       \
      __syncthreads();                                                        \
    } while (0)

  #pragma unroll 1
  for (int kt2 = 0; kt2 < DM; kt2 += 128) {
    PITER(kt2,      0, 1);
    PITER(kt2 + 64, 1, 0);
  }
  #undef PITER
}

// Merged projections, grid (768), 512 threads: id<512 Q/K; id>=512 V^T
__global__ __launch_bounds__(512) void proj_gemm(
    const unsigned short* __restrict__ X,
    const unsigned short* __restrict__ Wq,
    const unsigned short* __restrict__ Wk,
    const unsigned short* __restrict__ Wv,
    unsigned short* __restrict__ Qo,
    unsigned short* __restrict__ Ko,
    unsigned short* __restrict__ Vt)
{
  __shared__ __align__(16) unsigned short As[2 * 128 * 64];   // 32 KiB
  __shared__ __align__(16) unsigned short Bs[2 * 128 * 64];   // 32 KiB
  const int id = blockIdx.x;
  const int lane = threadIdx.x & 63;
  const int wave = threadIdx.x >> 6;
  const int wm = wave >> 2, wn = wave & 3;
  const int cn = lane & 15, quad = lane >> 4;
  f32x4 acc[4][2];

  if (id < 512) {
    const int m0   = (id & 31) * 128;
    const int by   = id >> 5;
    const int wsel = by >> 3;
    const int n0   = (by & 7) * 128;
    gemm_tile_db8(X, wsel ? Wk : Wq, m0, n0, As, Bs, acc);

    const float qscl = wsel ? 1.0f : 0.180336881f;   // 0.125 * log2(e)
    unsigned short* O = wsel ? Ko : Qo;
    #pragma unroll
    for (int i = 0; i < 4; ++i)
      #pragma unroll
      for (int j = 0; j < 2; ++j)
        #pragma unroll
        for (int r = 0; r < 4; ++r) {
          const int row = m0 + wm * 64 + i * 16 + quad * 4 + r;
          const int col = n0 + wn * 32 + j * 16 + cn;
          const int h = col >> 6, d = col & 63;
          O[(size_t)(h * LSEQ + row) * DH + d] = f2bf(acc[i][j][r] * qscl);
        }
  } else {
    const int vid = id - 512;
    const int m0 = (vid & 7) * 128;    // d-block (H*DH)
    const int n0 = (vid >> 3) * 128;   // token-block
    gemm_tile_db8(Wv, X, m0, n0, As, Bs, acc);

    #pragma unroll
    for (int i = 0; i < 4; ++i)
      #pragma unroll
      for (int j = 0; j < 2; ++j)
        #pragma unroll
        for (int r = 0; r < 4; ++r) {
          const int row = m0 + wm * 64 + i * 16 + quad * 4 + r;   // d
          const int col = n0 + wn * 32 + j * 16 + cn;             // token
          Vt[(size_t)row * LSEQ + col] = f2bf(acc[i][j][r]);
        }
  }
}

// Output projection, 64x128 tiles, grid (64,8) = 512 blocks = 2/CU.
// R20: + double-buffered stage-ahead (R19-proven): one barrier per K-step,
// loads issued before compute. LDS 48 KiB. Same numerics as R16.
__global__ __launch_bounds__(256) void out_gemm(
    const unsigned short* __restrict__ X,
    const unsigned short* __restrict__ W,
    float* __restrict__ O)
{
  __shared__ __align__(16) unsigned short As2[2 * 64 * 64];    // 16 KiB
  __shared__ __align__(16) unsigned short Bs[2 * 128 * 64];    // 32 KiB
  const int m0 = blockIdx.x * 64;
  const int n0 = blockIdx.y * 128;
  const int tid  = threadIdx.x;
  const int lane = tid & 63;
  const int wave = tid >> 6;
  const int wm = wave >> 1, wn = wave & 1;
  const int fr = lane & 15, quad = lane >> 4;
  const int sw = fr & 7;

  const f32x4 zero = {0.f, 0.f, 0.f, 0.f};
  f32x4 acc[2][4];
  #pragma unroll
  for (int i = 0; i < 2; ++i)
    #pragma unroll
    for (int j = 0; j < 4; ++j)
      acc[i][j] = zero;

  const unsigned short* ga[2];
  int lca[2];
  #pragma unroll
  for (int cc = 0; cc < 2; ++cc) {
    const int c = tid + cc * 256;
    const int row = c >> 3;
    const int gpp = (c & 7) ^ (row & 7);
    ga[cc] = X + (size_t)(m0 + row) * DM + gpp * 8;
    lca[cc] = c * 16;
  }
  const unsigned short* gb[4];
  int lcb[4];
  #pragma unroll
  for (int cc = 0; cc < 4; ++cc) {
    const int c = tid + cc * 256;
    const int row = c >> 3;
    const int gpp = (c & 7) ^ (row & 7);
    gb[cc] = W + (size_t)(n0 + row) * DM + gpp * 8;
    lcb[cc] = c * 16;
  }
  char* laA = (char*)As2;
  char* laB = (char*)Bs;

  // prologue: stage tile 0 into buffer 0
  #pragma unroll
  for (int cc = 0; cc < 2; ++cc) gl2lds16(ga[cc], laA + lca[cc]);
  #pragma unroll
  for (int cc = 0; cc < 4; ++cc) gl2lds16(gb[cc], laB + lcb[cc]);
  __syncthreads();

  #define OITER(KT, CUR, NXT)                                                 \
    do {                                                                      \
      if ((KT) + 64 < DM) {                                                   \
        _Pragma("unroll")                                                     \
        for (int cc = 0; cc < 2; ++cc)                                        \
          gl2lds16(ga[cc] + (KT) + 64, laA + (NXT) * 8192 + lca[cc]);         \
        _Pragma("unroll")                                                     \
        for (int cc = 0; cc < 4; ++cc)                                        \
          gl2lds16(gb[cc] + (KT) + 64, laB + (NXT) * 16384 + lcb[cc]);        \
      }                                                                       \
      const unsigned short* As_ = As2 + (CUR) * 4096;                         \
      const unsigned short* Bs_ = Bs + (CUR) * 8192;                          \
      _Pragma("unroll")                                                       \
      for (int s = 0; s < 2; ++s) {                                           \
        bf16x8 a[2], b[4];                                                    \
        _Pragma("unroll")                                                     \
        for (int t = 0; t < 2; ++t)                                           \
          a[t] = *(const bf16x8*)(As_ + (wm * 32 + t * 16 + fr) * 64          \
                                      + (((s * 4 + quad) ^ sw) * 8));         \
        _Pragma("unroll")                                                     \
        for (int t = 0; t < 4; ++t)                                           \
          b[t] = *(const bf16x8*)(Bs_ + (wn * 64 + t * 16 + fr) * 64          \
                                      + (((s * 4 + quad) ^ sw) * 8));         \
        __builtin_amdgcn_s_setprio(1);                                        \
        _Pragma("unroll")                                                     \
        for (int i = 0; i < 2; ++i)                                           \
          _Pragma("unroll")                                                   \
          for (int j = 0; j < 4; ++j)                                         \
            acc[i][j] = __builtin_amdgcn_mfma_f32_16x16x32_bf16(              \
                a[i], b[j], acc[i][j], 0, 0, 0);                              \
        __builtin_amdgcn_s_setprio(0);                                        \
      }                                                                       \
      __syncthreads();                                                        \
    } while (0)

  #pragma unroll 1
  for (int kt2 = 0; kt2 < DM; kt2 += 128) {
    OITER(kt2,      0, 1);
    OITER(kt2 + 64, 1, 0);
  }
  #undef OITER

  const int cn = lane & 15;
  #pragma unroll
  for (int i = 0; i < 2; ++i)
    #pragma unroll
    for (int j = 0; j < 4; ++j)
      #pragma unroll
      for (int r = 0; r < 4; ++r) {
        const int row = m0 + wm * 32 + i * 16 + quad * 4 + r;
        const int col = n0 + wn * 64 + j * 16 + cn;
        O[(size_t)row * DM + col] = acc[i][j][r];
      }
}

// Flash sliding-window attention (R15 form, frozen):
// 8 waves x 128 queries per block; K/V staged once per block into padded LDS
// (double-buffered, reg-staged); waves skip fully-masked tiles; mask VALU
// only on partially-masked tiles; T5 setprio around MFMA clusters.
#define PSTR 72
__global__ __launch_bounds__(512) void attn_fwd(
    const unsigned short* __restrict__ Q,
    const unsigned short* __restrict__ K,
    const unsigned short* __restrict__ Vt,
    unsigned short* __restrict__ Oa)
{
  __shared__ unsigned short Ks[2][64 * PSTR];   // 9216 B each
  __shared__ unsigned short Vs[2][64 * PSTR];
  __shared__ unsigned short Pl[8][16 * PSTR];   // per-wave P tiles
  const int id   = blockIdx.x;
  const int h    = (id & 7) | ((id >> 8) << 3);
  const int bq0  = ((id >> 3) & 31) * 128;
  const int tid  = threadIdx.x;
  const int wave = tid >> 6;
  const int lane = tid & 63;
  const int n = lane & 15, quad = lane >> 4;
  const int q0 = bq0 + wave * 16;
  unsigned short* pl = Pl[wave];

  const size_t qbase = ((size_t)(h * LSEQ + q0 + n)) * DH + quad * 8;
  const bf16x8 aq0 = *(const bf16x8*)(Q + qbase);   // Q pre-scaled by 0.125*log2e
  const bf16x8 aq1 = *(const bf16x8*)(Q + qbase + 32);

  const int lo = (bq0 >= WIN) ? (bq0 - WIN) : 0;    // first 64-key tile
  const int hi = bq0 + 128;

  // staging map: 512 x 16B chunks per tile; thread t handles chunk t.
  const int krow = tid >> 3, part = tid & 7;
  const size_t kg = ((size_t)(h * LSEQ + krow)) * DH + part * 8;
  const size_t vg = ((size_t)(h * DH + krow)) * LSEQ + part * 8;
  const int ld = krow * PSTR + part * 8;

  // prologue: stage tile 0 into buffer 0
  {
    *(bf16x8*)(Ks[0] + ld) = *(const bf16x8*)(K  + kg + (size_t)lo * DH);
    *(bf16x8*)(Vs[0] + ld) = *(const bf16x8*)(Vt + vg + lo);
  }
  __syncthreads();

  const f32x4 zero = {0.f, 0.f, 0.f, 0.f};
  f32x4 acc[4] = {zero, zero, zero, zero};
  float li[4] = {0.f, 0.f, 0.f, 0.f};

  int t = 0;
  for (int jb = lo; jb < hi; jb += 64, ++t) {
    const int buf = t & 1;
    const bool more = (jb + 64 < hi);
    // ---- issue next tile's global loads (overlap entire compute phase)
    bf16x8 nk, nv;
    if (more) {
      nk = *(const bf16x8*)(K  + kg + (size_t)(jb + 64) * DH);
      nv = *(const bf16x8*)(Vt + vg + (jb + 64));
    }
    // wave-level relevance: any of this wave's 16 rows attends a key here?
    const bool active = (jb <= q0 + 15) && (jb + 63 >= q0 - (WIN - 1));
    if (active) {
      const unsigned short* ks = Ks[buf];
      const unsigned short* vs = Vs[buf];
      // ---- QK scores from LDS K
      f32x4 s[4];
      __builtin_amdgcn_s_setprio(1);
      #pragma unroll
      for (int u = 0; u < 4; ++u) {
        const bf16x8 kb0 = *(const bf16x8*)(ks + (u * 16 + n) * PSTR + quad * 8);
        const bf16x8 kb1 = *(const bf16x8*)(ks + (u * 16 + n) * PSTR + 32 + quad * 8);
        f32x4 c = zero;
        c = __builtin_amdgcn_mfma_f32_16x16x32_bf16(aq0, kb0, c, 0, 0, 0);
        c = __builtin_amdgcn_mfma_f32_16x16x32_bf16(aq1, kb1, c, 0, 0, 0);
        s[u] = c;
      }
      __builtin_amdgcn_s_setprio(0);
      // ---- fixed-shift exp2 + per-lane partial denominator
      const bool nomask = (jb + 63 <= q0) && (jb >= q0 + 15 - (WIN - 1));
      if (nomask) {
        #pragma unroll
        for (int u = 0; u < 4; ++u)
          #pragma unroll
          for (int r = 0; r < 4; ++r) {
            const float e = __builtin_exp2f(s[u][r] - 32.0f);
            s[u][r] = e;
            li[r] += e;
          }
      } else {
        #pragma unroll
        for (int u = 0; u < 4; ++u)
          #pragma unroll
          for (int r = 0; r < 4; ++r) {
            const int qi = q0 + quad * 4 + r;
            const int kj = jb + u * 16 + n;
            const bool ok = (kj <= qi) && (kj + WIN > qi);
            const float e = __builtin_exp2f(ok ? s[u][r] - 32.0f : -1e30f);
            s[u][r] = e;
            li[r] += e;
          }
      }
      // ---- P: C-layout regs -> per-wave LDS -> A-operand layout
      #pragma unroll
      for (int u = 0; u < 4; ++u)
        #pragma unroll
        for (int r = 0; r < 4; ++r)
          pl[(quad * 4 + r) * PSTR + u * 16 + n] = f2bf(s[u][r]);
      asm volatile("s_waitcnt lgkmcnt(0)" ::: "memory");   // wave-private LDS fence
      const bf16x8 pa0 = *(const bf16x8*)(pl + n * PSTR + quad * 8);
      const bf16x8 pa1 = *(const bf16x8*)(pl + n * PSTR + 32 + quad * 8);
      // ---- PV from LDS V
      __builtin_amdgcn_s_setprio(1);
      #pragma unroll
      for (int ct = 0; ct < 4; ++ct) {
        const bf16x8 vb0 = *(const bf16x8*)(vs + (ct * 16 + n) * PSTR + quad * 8);
        const bf16x8 vb1 = *(const bf16x8*)(vs + (ct * 16 + n) * PSTR + 32 + quad * 8);
        acc[ct] = __builtin_amdgcn_mfma_f32_16x16x32_bf16(pa0, vb0, acc[ct], 0, 0, 0);
        acc[ct] = __builtin_amdgcn_mfma_f32_16x16x32_bf16(pa1, vb1, acc[ct], 0, 0, 0);
      }
      __builtin_amdgcn_s_setprio(0);
    }
    // ---- write next tile into the other buffer, then one barrier
    if (more) {
      *(bf16x8*)(Ks[buf ^ 1] + ld) = nk;
      *(bf16x8*)(Vs[buf ^ 1] + ld) = nv;
    }
    __syncthreads();
  }

  // ---- single cross-lane denominator reduction
  float rd[4];
  #pragma unroll
  for (int r = 0; r < 4; ++r) {
    float v = li[r];
    v += __shfl_xor(v, 1);
    v += __shfl_xor(v, 2);
    v += __shfl_xor(v, 4);
    v += __shfl_xor(v, 8);
    rd[r] = 1.0f / v;
  }
  #pragma unroll
  for (int ct = 0; ct < 4; ++ct)
    #pragma unroll
    for (int r = 0; r < 4; ++r) {
      const int row = q0 + quad * 4 + r;
      const int col = h * DH + ct * 16 + n;
      Oa[(size_t)row * DM + col] = f2bf(acc[ct][r] * rd[r]);
    }
}

extern "C" void kernel_launch(void* const* d_in, const int* in_sizes, int n_in,
                              void* d_out, int out_size, void* d_ws, size_t ws_size,
                              hipStream_t stream) {
  const float* x  = (const float*)d_in[0];
  const float* Wq = (const float*)d_in[1];
  const float* Wk = (const float*)d_in[2];
  const float* Wv = (const float*)d_in[3];
  const float* Wo = (const float*)d_in[4];
  float* out = (float*)d_out;               // fp32 output (proven R6)

  unsigned short* xb  = (unsigned short*)d_ws;            // [L][DM]    8 MiB
  unsigned short* Wqb = xb  + (size_t)LSEQ * DM;          // 2 MiB each
  unsigned short* Wkb = Wqb + (size_t)DM * DM;
  unsigned short* Wvb = Wkb + (size_t)DM * DM;
  unsigned short* Wob = Wvb + (size_t)DM * DM;
  unsigned short* Q    = Wob + (size_t)DM * DM;           // [H][L][64] 8 MiB (pre-scaled)
  unsigned short* K    = Q   + (size_t)LSEQ * DM;
  unsigned short* Vt   = K   + (size_t)LSEQ * DM;         // [H*DH][L]
  unsigned short* Attn = Vt  + (size_t)LSEQ * DM;         // [L][DM]
  // total 48 MiB (ws >= 64 MiB, proven R4)

  cvt_all<<<dim3(4096), 256, 0, stream>>>(x, Wq, Wk, Wv, Wo, xb);
  proj_gemm<<<dim3(768), 512, 0, stream>>>(xb, Wqb, Wkb, Wvb, Q, K, Vt);
  attn_fwd<<<dim3(512), 512, 0, stream>>>(Q, K, Vt, Attn);
  out_gemm<<<dim3(64, 8), 256, 0, stream>>>(Attn, Wob, out);
}